// Round 9
// baseline (329.519 us; speedup 1.0000x reference)
//
#include <hip/hip_runtime.h>

#define N_NODES 512
#define C_CH    128
#define S_SPEC  10
#define KT      50
#define NT      11

typedef _Float16 h8 __attribute__((ext_vector_type(8)));
typedef __fp16   g2 __attribute__((ext_vector_type(2)));   // cvt_pkrtz return type
typedef float f32x4 __attribute__((ext_vector_type(4)));

// K layout: 50 tiles x 32 slots; tile = 4 octets (one per lane-group g).
// Octet = (offA, offB, j0): slot i computes x[offA]*x[offB]*x[j0+i], j0 in {0,8}.
// N cols (o-major): nt 0..6 = k3, 7..9 = k2, 10 = k1; col = o (0..15).
__device__ h8 g_Bf[KT * NT * 64];   // B pre-swizzled to MFMA B-frag order [kt][nt][lane]
__device__ h8 g_Wf[128 * 64];       // wlin as A-frags: [mt*16+ks][lane], K-expanded (ir,cc)

__device__ __forceinline__ int fc_of(int kt)  { return kt < 43 ? 7 : (kt < 49 ? 3 : 1); }
__device__ __forceinline__ int ntb_of(int kt) { return kt < 43 ? 0 : (kt < 49 ? 7 : 10); }

__device__ __forceinline__ void o_to_iri(int o, int& ir, int& i) {
  if (o >= 9)      { ir = 3; i = o - 9; }
  else if (o >= 4) { ir = 2; i = o - 4; }
  else if (o >= 1) { ir = 1; i = o - 1; }
  else             { ir = 0; i = 0; }
}

__device__ int octet_desc(int Q) {
  if (Q < 172) {                     // order-3
    int q = Q;
    for (int a = 0; a < 16; ++a)
      for (int b = a; b < 16; ++b) {
        int no = (b < 8) ? 2 : 1;
        if (q < no) {
          int jb = (no == 1) ? 1 : q;          // b<8: q0->j0=0,q1->j0=8; b>=8: j0=8
          return a | (b << 5) | (jb << 10);
        }
        q -= no;
      }
  } else if (Q < 196) {              // order-2
    int q = Q - 172;
    for (int a = 0; a < 16; ++a) {
      int no = (a < 8) ? 2 : 1;
      if (q < no) {
        int jb = (no == 1) ? 1 : q;
        return a | (16 << 5) | (jb << 10);
      }
      q -= no;
    }
  } else if (Q < 198) {              // order-1
    return 16 | (16 << 5) | ((Q - 196) << 10);
  }
  return 17 | (17 << 5);             // pad (zero column)
}

// ---- merged build: blocks 0..319 build B fragments, 320..447 build W fragments ----
__global__ void build_all(const float* __restrict__ u1_0, const float* __restrict__ u1_1,
                          const float* __restrict__ u1_2, const float* __restrict__ u1_3,
                          const float* __restrict__ u2_0, const float* __restrict__ u2_1,
                          const float* __restrict__ u2_2, const float* __restrict__ u2_3,
                          const float* __restrict__ u3_0, const float* __restrict__ u3_1,
                          const float* __restrict__ u3_2, const float* __restrict__ u3_3,
                          const float* __restrict__ wlin) {
  const int bid = blockIdx.x;
  const int dis[4] = {1, 3, 5, 7};
  if (bid < 320) {
    int kt, nt;
    if (bid < 301)      { kt = bid / 7; nt = bid % 7; }
    else if (bid < 319) { int e = bid - 301; kt = 43 + e / 3; nt = 7 + e % 3; }
    else                { kt = 49; nt = 10; }

    const int l = threadIdx.x;
    const int o = l & 15;
    int ir, ii; o_to_iri(o, ir, ii);
    const int di = dis[ir];
    const float* u1s[4] = {u1_0, u1_1, u1_2, u1_3};
    const float* u2s[4] = {u2_0, u2_1, u2_2, u2_3};
    const float* u3s[4] = {u3_0, u3_1, u3_2, u3_3};

    const int rt = octet_desc(kt * 4 + (l >> 4));
    const int oA = rt & 31, oB = (rt >> 5) & 31, j0 = ((rt >> 10) & 1) * 8;

    h8 v;
#pragma unroll
    for (int i = 0; i < 8; ++i) {
      const int j = j0 + i;
      float val = 0.f;
      if (oA < 16 && oB < 16) {              // order-3, canonical a<=b<=j
        if (j >= oB) {
          const float* u = u3s[ir];
          int a = oA, b = oB;
          int P[6][3] = {{a,b,j},{a,j,b},{b,a,j},{b,j,a},{j,a,b},{j,b,a}};
          for (int p = 0; p < 6; ++p) {
            bool dup = false;
            for (int r = 0; r < p; ++r)
              if (P[r][0] == P[p][0] && P[r][1] == P[p][1] && P[r][2] == P[p][2]) { dup = true; break; }
            if (!dup)
              val += u[(((P[p][0] * 16 + P[p][1]) * 16 + P[p][2]) * 7 + nt) * di + ii];
          }
        }
      } else if (oA < 16 && oB == 16) {      // order-2 (oA <= j)
        if (j >= oA) {
          const int k2 = nt - 7;
          const float* u = u2s[ir];
          val = u[((oA * 16 + j) * 3 + k2) * di + ii];
          if (j != oA) val += u[((j * 16 + oA) * 3 + k2) * di + ii];
        }
      } else if (oA == 16) {                 // order-1
        val = u1s[ir][j * di + ii];
      }
      v[i] = (_Float16)val;
    }
    g_Bf[((size_t)kt * NT + nt) * 64 + l] = v;
  } else {
    // wlin -> fp16 A-frags over expanded K = (ir*128+cc), scaled by 1/sqrt(128)
    const int id = (bid - 320) * 64 + threadIdx.x;   // 8192 total
    const int l = id & 63, ks = (id >> 6) & 15, mt = id >> 10;
    const int f = mt * 16 + (l & 15);
    const float inv = 0.08838834764831845f;
    h8 v;
#pragma unroll
    for (int i = 0; i < 8; ++i) {
      const int k = ks * 32 + (l >> 4) * 8 + i;
      const int ir = k >> 7, cc = k & 127;
      v[i] = (_Float16)(wlin[((size_t)ir * C_CH + cc) * C_CH + f] * inv);
    }
    g_Wf[(mt * 16 + ks) * 64 + l] = v;
  }
}

// ---------------- fused main kernel: K-split over blockIdx.y, atomic merge ----------------

#define MFMA16(A, B, C) __builtin_amdgcn_mfma_f32_16x16x32_f16(A, B, C, 0, 0, 0)

union H8U { h8 v; g2 p[4]; };

__global__ __launch_bounds__(512, 4) void eqp_mm(
    const float* __restrict__ x, const int* __restrict__ specie,
    const float* __restrict__ w1, const float* __restrict__ w2,
    const float* __restrict__ w3, float* __restrict__ out) {
  __shared__ __align__(16) char bs[2][28 * 1024];   // B chunk double buffer (Ef aliases later)
  __shared__ float xT[2][128][18];                  // cols 0..15 x, 16 = 1, 17 = 0
  __shared__ int rtab[KT * 4];

  const int t = threadIdx.x;
  const int l = t & 63;
  const int w = t >> 6;
  const int g = l >> 4;
  const int n0 = blockIdx.x * 2;
  const int ksp = blockIdx.y;          // K-half: 0 -> tiles 0..24, 1 -> 25..49

  {  // stage xT + rtab
    const int p = t >> 8, c = (t >> 1) & 127, half = t & 1;
    const float* xp = x + ((size_t)(n0 + p) * C_CH + c) * 16 + half * 8;
    const float4 v0 = *(const float4*)xp, v1 = *(const float4*)(xp + 4);
    float* row = &xT[p][c][half * 8];
    row[0] = v0.x; row[1] = v0.y; row[2] = v0.z; row[3] = v0.w;
    row[4] = v1.x; row[5] = v1.y; row[6] = v1.z; row[7] = v1.w;
    if (half == 1) { xT[p][c][16] = 1.f; xT[p][c][17] = 0.f; }
    if (t < KT * 4) rtab[t] = octet_desc(t);
  }

  const int ch = w * 16 + (l & 15);
  const int s0 = specie[n0], s1 = specie[n0 + 1];

  float4 x0a, x0b, x0c, x0d, x1a, x1b, x1c, x1d;
  {
    const float4* p0 = (const float4*)(x + ((size_t)n0 * C_CH + ch) * 16);
    x0a = p0[0]; x0b = p0[1]; x0c = p0[2]; x0d = p0[3];
    const float4* p1 = (const float4*)(x + ((size_t)(n0 + 1) * C_CH + ch) * 16);
    x1a = p1[0]; x1b = p1[1]; x1c = p1[2]; x1d = p1[3];
  }

  f32x4 acc[2][NT];
#pragma unroll
  for (int p = 0; p < 2; ++p)
#pragma unroll
    for (int i = 0; i < NT; ++i) acc[p][i] = (f32x4){0.f, 0.f, 0.f, 0.f};

  const int T0 = ksp * 25;
  const int tEnd = T0 + 25;

  h8 tv[4]; int dst[4];

  auto issue = [&](int cs, int ntl) {
    int nf = 0;
#pragma unroll
    for (int tt = 0; tt < 4; ++tt) if (tt < ntl && cs + tt < tEnd) nf += fc_of(cs + tt);
#pragma unroll
    for (int slot = 0; slot < 4; ++slot) {
      const int fi = slot * 8 + w;
      const bool ok = fi < nf;
      int kt = cs, rem = fi;
      if (ok) { while (rem >= fc_of(kt)) { rem -= fc_of(kt); ++kt; } }
      dst[slot] = ok ? fi : -1;
      if (ok) tv[slot] = g_Bf[((size_t)kt * NT + (ntb_of(kt) + rem)) * 64 + l];
    }
  };
  auto wr = [&](char* buf) {
#pragma unroll
    for (int slot = 0; slot < 4; ++slot)
      if (dst[slot] >= 0) *(h8*)&buf[(size_t)dst[slot] * 1024 + (size_t)l * 16] = tv[slot];
  };

#define BRD(i) (*(const h8*)&buf[(size_t)(fb2 + (i)) * 1024 + (size_t)l * 16])

  auto consume = [&](int cs, int ntl, const char* buf) {
    int fb2 = 0;
#pragma unroll
    for (int tt = 0; tt < 4; ++tt) {
      if (tt >= ntl || cs + tt >= tEnd) continue;
      const int kt = cs + tt;
      const int rt_ = rtab[kt * 4 + g];
      const int oA_ = rt_ & 31, oB_ = (rt_ >> 5) & 31, jb_ = (rt_ >> 10) & 1;
      const float xab0 = xT[0][ch][oA_] * xT[0][ch][oB_];
      const float xab1 = xT[1][ch][oA_] * xT[1][ch][oB_];
      const float4 lo0 = jb_ ? x0c : x0a, hi0 = jb_ ? x0d : x0b;
      const float4 lo1 = jb_ ? x1c : x1a, hi1 = jb_ ? x1d : x1b;
      H8U af0, af1;
      af0.p[0] = __builtin_amdgcn_cvt_pkrtz(xab0 * lo0.x, xab0 * lo0.y);
      af0.p[1] = __builtin_amdgcn_cvt_pkrtz(xab0 * lo0.z, xab0 * lo0.w);
      af0.p[2] = __builtin_amdgcn_cvt_pkrtz(xab0 * hi0.x, xab0 * hi0.y);
      af0.p[3] = __builtin_amdgcn_cvt_pkrtz(xab0 * hi0.z, xab0 * hi0.w);
      af1.p[0] = __builtin_amdgcn_cvt_pkrtz(xab1 * lo1.x, xab1 * lo1.y);
      af1.p[1] = __builtin_amdgcn_cvt_pkrtz(xab1 * lo1.z, xab1 * lo1.w);
      af1.p[2] = __builtin_amdgcn_cvt_pkrtz(xab1 * hi1.x, xab1 * hi1.y);
      af1.p[3] = __builtin_amdgcn_cvt_pkrtz(xab1 * hi1.z, xab1 * hi1.w);
      if (kt < 43) {
        h8 b0 = BRD(0), b1 = BRD(1), b2 = BRD(2), b3 = BRD(3), b4 = BRD(4), b5 = BRD(5), b6 = BRD(6);
        acc[0][0] = MFMA16(af0.v, b0, acc[0][0]); acc[1][0] = MFMA16(af1.v, b0, acc[1][0]);
        acc[0][1] = MFMA16(af0.v, b1, acc[0][1]); acc[1][1] = MFMA16(af1.v, b1, acc[1][1]);
        acc[0][2] = MFMA16(af0.v, b2, acc[0][2]); acc[1][2] = MFMA16(af1.v, b2, acc[1][2]);
        acc[0][3] = MFMA16(af0.v, b3, acc[0][3]); acc[1][3] = MFMA16(af1.v, b3, acc[1][3]);
        acc[0][4] = MFMA16(af0.v, b4, acc[0][4]); acc[1][4] = MFMA16(af1.v, b4, acc[1][4]);
        acc[0][5] = MFMA16(af0.v, b5, acc[0][5]); acc[1][5] = MFMA16(af1.v, b5, acc[1][5]);
        acc[0][6] = MFMA16(af0.v, b6, acc[0][6]); acc[1][6] = MFMA16(af1.v, b6, acc[1][6]);
        fb2 += 7;
      } else if (kt < 49) {
        h8 b0 = BRD(0), b1 = BRD(1), b2 = BRD(2);
        acc[0][7] = MFMA16(af0.v, b0, acc[0][7]); acc[1][7] = MFMA16(af1.v, b0, acc[1][7]);
        acc[0][8] = MFMA16(af0.v, b1, acc[0][8]); acc[1][8] = MFMA16(af1.v, b1, acc[1][8]);
        acc[0][9] = MFMA16(af0.v, b2, acc[0][9]); acc[1][9] = MFMA16(af1.v, b2, acc[1][9]);
        fb2 += 3;
      } else {
        h8 b0 = BRD(0);
        acc[0][10] = MFMA16(af0.v, b0, acc[0][10]); acc[1][10] = MFMA16(af1.v, b0, acc[1][10]);
        fb2 += 1;
      }
    }
  };

  // ---- pipelined main loop: 6 chunks of 4 tiles + 1 tail tile; 1 barrier/chunk ----
  issue(T0, 4);
  __syncthreads();           // xT/rtab visible
  wr(bs[0]);
  __syncthreads();
#pragma unroll 1
  for (int ck = 0; ck < 7; ++ck) {
    const int cs = T0 + ck * 4;
    const int ntl = (ck < 6) ? 4 : 1;
    if (ck < 6) issue(cs + 4, (ck < 5) ? 4 : 1);
    consume(cs, ntl, bs[ck & 1]);
    if (ck < 6) {
      wr(bs[(ck & 1) ^ 1]);   // that buffer was consumed a chunk ago, barrier-separated
      __syncthreads();
    }
  }
  __syncthreads();   // all B reads done; safe to alias bs as Ef

  // ---- species fold -> Ef (fp16, K-expanded (ir,cc)), zero-padded ----
  _Float16* Ef = (_Float16*)&bs[0][0];   // [p][ks(16)][lg(4)][o(16)][i(8)] = 32 KB
  {
    float4 z4 = {0.f, 0.f, 0.f, 0.f};
    float4* zp = (float4*)&bs[0][0];
    zp[t] = z4; zp[t + 512] = z4; zp[t + 1024] = z4; zp[t + 1536] = z4;
  }
  __syncthreads();
  {
    const int o = l & 15;
    int ir, ii; o_to_iri(o, ir, ii); (void)ii;
    const int cb = w * 16 + g * 4;
#pragma unroll
    for (int p = 0; p < 2; ++p) {
      const int sp = p ? s1 : s0;
      float tot[4] = {0.f, 0.f, 0.f, 0.f};
#pragma unroll
      for (int k = 0; k < 7; ++k) {
        const float4 wv = *(const float4*)(w3 + ((size_t)(ir * S_SPEC + sp) * 7 + k) * C_CH + cb);
        tot[0] = fmaf(wv.x, acc[p][k][0], tot[0]);
        tot[1] = fmaf(wv.y, acc[p][k][1], tot[1]);
        tot[2] = fmaf(wv.z, acc[p][k][2], tot[2]);
        tot[3] = fmaf(wv.w, acc[p][k][3], tot[3]);
      }
#pragma unroll
      for (int k = 0; k < 3; ++k) {
        const float4 wv = *(const float4*)(w2 + ((size_t)(ir * S_SPEC + sp) * 3 + k) * C_CH + cb);
        tot[0] = fmaf(wv.x, acc[p][7 + k][0], tot[0]);
        tot[1] = fmaf(wv.y, acc[p][7 + k][1], tot[1]);
        tot[2] = fmaf(wv.z, acc[p][7 + k][2], tot[2]);
        tot[3] = fmaf(wv.w, acc[p][7 + k][3], tot[3]);
      }
      {
        const float4 wv = *(const float4*)(w1 + (size_t)(ir * S_SPEC + sp) * C_CH + cb);
        tot[0] = fmaf(wv.x, acc[p][10][0], tot[0]);
        tot[1] = fmaf(wv.y, acc[p][10][1], tot[1]);
        tot[2] = fmaf(wv.z, acc[p][10][2], tot[2]);
        tot[3] = fmaf(wv.w, acc[p][10][3], tot[3]);
      }
#pragma unroll
      for (int r = 0; r < 4; ++r) {
        const int k = ir * 128 + cb + r;   // expanded K index
        Ef[((((size_t)p * 16 + (k >> 5)) * 4 + ((k >> 3) & 3)) * 16 + o) * 8 + (k & 7)] =
            (_Float16)tot[r];
      }
    }
  }
  __syncthreads();

  // ---- wlin channel mix via MFMA; merge K-halves with atomicAdd ----
  {
    f32x4 D0 = {0.f, 0.f, 0.f, 0.f}, D1 = {0.f, 0.f, 0.f, 0.f};
#pragma unroll
    for (int ks = 0; ks < 16; ++ks) {
      const h8 aw = g_Wf[(w * 16 + ks) * 64 + l];
      const h8 b0 = *(const h8*)&Ef[(((size_t)0 * 16 + ks) * 4 + (l >> 4)) * 128 + (size_t)(l & 15) * 8];
      const h8 b1 = *(const h8*)&Ef[(((size_t)1 * 16 + ks) * 4 + (l >> 4)) * 128 + (size_t)(l & 15) * 8];
      D0 = MFMA16(aw, b0, D0);
      D1 = MFMA16(aw, b1, D1);
    }
    const int o = l & 15;
    int ir, ii; o_to_iri(o, ir, ii);
    const int dis[4]  = {1, 3, 5, 7};
    const int ooff[4] = {0, 128, 512, 1152};
#pragma unroll
    for (int p = 0; p < 2; ++p) {
      const f32x4 D = p ? D1 : D0;
      const size_t base = (size_t)(n0 + p) * 2048 + ooff[ir] + ii;
#pragma unroll
      for (int r = 0; r < 4; ++r) {
        const int f = w * 16 + (l >> 4) * 4 + r;
        atomicAdd(&out[base + (size_t)f * dis[ir]], D[r]);
      }
    }
  }
}

// ---------------- launch ----------------

extern "C" void kernel_launch(void* const* d_in, const int* in_sizes, int n_in,
                              void* d_out, int out_size, void* d_ws, size_t ws_size,
                              hipStream_t stream) {
  const float* x      = (const float*)d_in[0];
  const int*   specie = (const int*)d_in[1];

  const float *u1s[4], *u2s[4], *u3s[4];
  if (in_sizes[3] == 768) {  // interleaved dict order: u1_0,u2_0,u3_0,u1_1,...
    for (int i = 0; i < 4; ++i) {
      u1s[i] = (const float*)d_in[2 + 3 * i];
      u2s[i] = (const float*)d_in[3 + 3 * i];
      u3s[i] = (const float*)d_in[4 + 3 * i];
    }
  } else {                   // grouped order: u1_0..u1_3,u2_0..u2_3,u3_0..u3_3
    for (int i = 0; i < 4; ++i) {
      u1s[i] = (const float*)d_in[2 + i];
      u2s[i] = (const float*)d_in[6 + i];
      u3s[i] = (const float*)d_in[10 + i];
    }
  }
  const float* w1   = (const float*)d_in[14];
  const float* w2   = (const float*)d_in[15];
  const float* w3   = (const float*)d_in[16];
  const float* wlin = (const float*)d_in[17];
  float* out = (float*)d_out;
  (void)d_ws; (void)ws_size; (void)n_in;

  hipMemsetAsync(out, 0, (size_t)out_size * sizeof(float), stream);
  build_all<<<448, 64, 0, stream>>>(
      u1s[0], u1s[1], u1s[2], u1s[3],
      u2s[0], u2s[1], u2s[2], u2s[3],
      u3s[0], u3s[1], u3s[2], u3s[3], wlin);
  eqp_mm<<<dim3(N_NODES / 2, 2), 512, 0, stream>>>(x, specie, w1, w2, w3, out);
}

// Round 10
// 114.599 us; speedup vs baseline: 2.8754x; 2.8754x over previous
//
#include <hip/hip_runtime.h>

#define N_NODES 512
#define C_CH    128
#define S_SPEC  10
#define KT      50
#define NT      11

typedef _Float16 h8 __attribute__((ext_vector_type(8)));
typedef __fp16   g2 __attribute__((ext_vector_type(2)));   // cvt_pkrtz return type
typedef float f32x4 __attribute__((ext_vector_type(4)));

// K layout: 50 tiles x 32 slots; tile = 4 octets (one per lane-group g).
// Octet = (offA, offB, j0): slot i computes x[offA]*x[offB]*x[j0+i], j0 in {0,8}.
// N cols (o-major): nt 0..6 = k3, 7..9 = k2, 10 = k1; col = o (0..15).
__device__ h8 g_Bf[KT * NT * 64];   // B pre-swizzled to MFMA B-frag order [kt][nt][lane]
__device__ h8 g_Wf[128 * 64];       // wlin as A-frags: [mt*16+ks][lane], K-expanded (ir,cc)

__device__ __forceinline__ int fc_of(int kt)  { return kt < 43 ? 7 : (kt < 49 ? 3 : 1); }
__device__ __forceinline__ int ntb_of(int kt) { return kt < 43 ? 0 : (kt < 49 ? 7 : 10); }

__device__ __forceinline__ void o_to_iri(int o, int& ir, int& i) {
  if (o >= 9)      { ir = 3; i = o - 9; }
  else if (o >= 4) { ir = 2; i = o - 4; }
  else if (o >= 1) { ir = 1; i = o - 1; }
  else             { ir = 0; i = 0; }
}

__device__ int octet_desc(int Q) {
  if (Q < 172) {                     // order-3
    int q = Q;
    for (int a = 0; a < 16; ++a)
      for (int b = a; b < 16; ++b) {
        int no = (b < 8) ? 2 : 1;
        if (q < no) {
          int jb = (no == 1) ? 1 : q;          // b<8: q0->j0=0,q1->j0=8; b>=8: j0=8
          return a | (b << 5) | (jb << 10);
        }
        q -= no;
      }
  } else if (Q < 196) {              // order-2
    int q = Q - 172;
    for (int a = 0; a < 16; ++a) {
      int no = (a < 8) ? 2 : 1;
      if (q < no) {
        int jb = (no == 1) ? 1 : q;
        return a | (16 << 5) | (jb << 10);
      }
      q -= no;
    }
  } else if (Q < 198) {              // order-1
    return 16 | (16 << 5) | ((Q - 196) << 10);
  }
  return 17 | (17 << 5);             // pad (zero column)
}

// ---- merged build: blocks 0..319 build B fragments, 320..447 build W fragments ----
__global__ void build_all(const float* __restrict__ u1_0, const float* __restrict__ u1_1,
                          const float* __restrict__ u1_2, const float* __restrict__ u1_3,
                          const float* __restrict__ u2_0, const float* __restrict__ u2_1,
                          const float* __restrict__ u2_2, const float* __restrict__ u2_3,
                          const float* __restrict__ u3_0, const float* __restrict__ u3_1,
                          const float* __restrict__ u3_2, const float* __restrict__ u3_3,
                          const float* __restrict__ wlin) {
  const int bid = blockIdx.x;
  const int dis[4] = {1, 3, 5, 7};
  if (bid < 320) {
    int kt, nt;
    if (bid < 301)      { kt = bid / 7; nt = bid % 7; }
    else if (bid < 319) { int e = bid - 301; kt = 43 + e / 3; nt = 7 + e % 3; }
    else                { kt = 49; nt = 10; }

    const int l = threadIdx.x;
    const int o = l & 15;
    int ir, ii; o_to_iri(o, ir, ii);
    const int di = dis[ir];
    const float* u1s[4] = {u1_0, u1_1, u1_2, u1_3};
    const float* u2s[4] = {u2_0, u2_1, u2_2, u2_3};
    const float* u3s[4] = {u3_0, u3_1, u3_2, u3_3};

    const int rt = octet_desc(kt * 4 + (l >> 4));
    const int oA = rt & 31, oB = (rt >> 5) & 31, j0 = ((rt >> 10) & 1) * 8;

    h8 v;
#pragma unroll
    for (int i = 0; i < 8; ++i) {
      const int j = j0 + i;
      float val = 0.f;
      if (oA < 16 && oB < 16) {              // order-3, canonical a<=b<=j
        if (j >= oB) {
          const float* u = u3s[ir];
          int a = oA, b = oB;
          int P[6][3] = {{a,b,j},{a,j,b},{b,a,j},{b,j,a},{j,a,b},{j,b,a}};
          for (int p = 0; p < 6; ++p) {
            bool dup = false;
            for (int r = 0; r < p; ++r)
              if (P[r][0] == P[p][0] && P[r][1] == P[p][1] && P[r][2] == P[p][2]) { dup = true; break; }
            if (!dup)
              val += u[(((P[p][0] * 16 + P[p][1]) * 16 + P[p][2]) * 7 + nt) * di + ii];
          }
        }
      } else if (oA < 16 && oB == 16) {      // order-2 (oA <= j)
        if (j >= oA) {
          const int k2 = nt - 7;
          const float* u = u2s[ir];
          val = u[((oA * 16 + j) * 3 + k2) * di + ii];
          if (j != oA) val += u[((j * 16 + oA) * 3 + k2) * di + ii];
        }
      } else if (oA == 16) {                 // order-1
        val = u1s[ir][j * di + ii];
      }
      v[i] = (_Float16)val;
    }
    g_Bf[((size_t)kt * NT + nt) * 64 + l] = v;
  } else {
    // wlin -> fp16 A-frags over expanded K = (ir*128+cc), scaled by 1/sqrt(128)
    const int id = (bid - 320) * 64 + threadIdx.x;   // 8192 total
    const int l = id & 63, ks = (id >> 6) & 15, mt = id >> 10;
    const int f = mt * 16 + (l & 15);
    const float inv = 0.08838834764831845f;
    h8 v;
#pragma unroll
    for (int i = 0; i < 8; ++i) {
      const int k = ks * 32 + (l >> 4) * 8 + i;
      const int ir = k >> 7, cc = k & 127;
      v[i] = (_Float16)(wlin[((size_t)ir * C_CH + cc) * C_CH + f] * inv);
    }
    g_Wf[(mt * 16 + ks) * 64 + l] = v;
  }
}

// ---------------- fused main kernel: K-split over blockIdx.y, atomic merge ----------------
// NOTE: no min-waves in __launch_bounds__ — R1/R4/R8 all spilled when the allocator was
// capped below live-register demand. Occupancy is controlled via LDS (75.6 KB -> 2 blocks/CU).

#define MFMA16(A, B, C) __builtin_amdgcn_mfma_f32_16x16x32_f16(A, B, C, 0, 0, 0)

union H8U { h8 v; g2 p[4]; };

__global__ __launch_bounds__(512, 1) void eqp_mm(
    const float* __restrict__ x, const int* __restrict__ specie,
    const float* __restrict__ w1, const float* __restrict__ w2,
    const float* __restrict__ w3, float* __restrict__ out) {
  __shared__ __align__(16) char bs[2][28 * 1024];   // B chunk double buffer (Ef aliases later)
  __shared__ float xT[2][128][18];                  // cols 0..15 x, 16 = 1, 17 = 0
  __shared__ int rtab[KT * 4];

  const int t = threadIdx.x;
  const int l = t & 63;
  const int w = t >> 6;
  const int g = l >> 4;
  const int n0 = blockIdx.x * 2;
  const int ksp = blockIdx.y;          // K-half: 0 -> tiles 0..24, 1 -> 25..49

  {  // stage xT + rtab
    const int p = t >> 8, c = (t >> 1) & 127, half = t & 1;
    const float* xp = x + ((size_t)(n0 + p) * C_CH + c) * 16 + half * 8;
    const float4 v0 = *(const float4*)xp, v1 = *(const float4*)(xp + 4);
    float* row = &xT[p][c][half * 8];
    row[0] = v0.x; row[1] = v0.y; row[2] = v0.z; row[3] = v0.w;
    row[4] = v1.x; row[5] = v1.y; row[6] = v1.z; row[7] = v1.w;
    if (half == 1) { xT[p][c][16] = 1.f; xT[p][c][17] = 0.f; }
    if (t < KT * 4) rtab[t] = octet_desc(t);
  }

  const int ch = w * 16 + (l & 15);
  const int s0 = specie[n0], s1 = specie[n0 + 1];

  float4 x0a, x0b, x0c, x0d, x1a, x1b, x1c, x1d;
  {
    const float4* p0 = (const float4*)(x + ((size_t)n0 * C_CH + ch) * 16);
    x0a = p0[0]; x0b = p0[1]; x0c = p0[2]; x0d = p0[3];
    const float4* p1 = (const float4*)(x + ((size_t)(n0 + 1) * C_CH + ch) * 16);
    x1a = p1[0]; x1b = p1[1]; x1c = p1[2]; x1d = p1[3];
  }

  f32x4 acc[2][NT];
#pragma unroll
  for (int p = 0; p < 2; ++p)
#pragma unroll
    for (int i = 0; i < NT; ++i) acc[p][i] = (f32x4){0.f, 0.f, 0.f, 0.f};

  const int T0 = ksp * 25;
  const int tEnd = T0 + 25;

  h8 tv[4]; int dst[4];

  auto issue = [&](int cs, int ntl) {
    int nf = 0;
#pragma unroll
    for (int tt = 0; tt < 4; ++tt) if (tt < ntl && cs + tt < tEnd) nf += fc_of(cs + tt);
#pragma unroll
    for (int slot = 0; slot < 4; ++slot) {
      const int fi = slot * 8 + w;
      const bool ok = fi < nf;
      int kt = cs, rem = fi;
      if (ok) { while (rem >= fc_of(kt)) { rem -= fc_of(kt); ++kt; } }
      dst[slot] = ok ? fi : -1;
      if (ok) tv[slot] = g_Bf[((size_t)kt * NT + (ntb_of(kt) + rem)) * 64 + l];
    }
  };
  auto wr = [&](char* buf) {
#pragma unroll
    for (int slot = 0; slot < 4; ++slot)
      if (dst[slot] >= 0) *(h8*)&buf[(size_t)dst[slot] * 1024 + (size_t)l * 16] = tv[slot];
  };

#define BRD(i) (*(const h8*)&buf[(size_t)(fb2 + (i)) * 1024 + (size_t)l * 16])

  auto consume = [&](int cs, int ntl, const char* buf) {
    int fb2 = 0;
#pragma unroll
    for (int tt = 0; tt < 4; ++tt) {
      if (tt >= ntl || cs + tt >= tEnd) continue;
      const int kt = cs + tt;
      const int rt_ = rtab[kt * 4 + g];
      const int oA_ = rt_ & 31, oB_ = (rt_ >> 5) & 31, jb_ = (rt_ >> 10) & 1;
      const float xab0 = xT[0][ch][oA_] * xT[0][ch][oB_];
      const float xab1 = xT[1][ch][oA_] * xT[1][ch][oB_];
      const float4 lo0 = jb_ ? x0c : x0a, hi0 = jb_ ? x0d : x0b;
      const float4 lo1 = jb_ ? x1c : x1a, hi1 = jb_ ? x1d : x1b;
      H8U af0, af1;
      af0.p[0] = __builtin_amdgcn_cvt_pkrtz(xab0 * lo0.x, xab0 * lo0.y);
      af0.p[1] = __builtin_amdgcn_cvt_pkrtz(xab0 * lo0.z, xab0 * lo0.w);
      af0.p[2] = __builtin_amdgcn_cvt_pkrtz(xab0 * hi0.x, xab0 * hi0.y);
      af0.p[3] = __builtin_amdgcn_cvt_pkrtz(xab0 * hi0.z, xab0 * hi0.w);
      af1.p[0] = __builtin_amdgcn_cvt_pkrtz(xab1 * lo1.x, xab1 * lo1.y);
      af1.p[1] = __builtin_amdgcn_cvt_pkrtz(xab1 * lo1.z, xab1 * lo1.w);
      af1.p[2] = __builtin_amdgcn_cvt_pkrtz(xab1 * hi1.x, xab1 * hi1.y);
      af1.p[3] = __builtin_amdgcn_cvt_pkrtz(xab1 * hi1.z, xab1 * hi1.w);
      if (kt < 43) {
        h8 b0 = BRD(0), b1 = BRD(1), b2 = BRD(2), b3 = BRD(3), b4 = BRD(4), b5 = BRD(5), b6 = BRD(6);
        acc[0][0] = MFMA16(af0.v, b0, acc[0][0]); acc[1][0] = MFMA16(af1.v, b0, acc[1][0]);
        acc[0][1] = MFMA16(af0.v, b1, acc[0][1]); acc[1][1] = MFMA16(af1.v, b1, acc[1][1]);
        acc[0][2] = MFMA16(af0.v, b2, acc[0][2]); acc[1][2] = MFMA16(af1.v, b2, acc[1][2]);
        acc[0][3] = MFMA16(af0.v, b3, acc[0][3]); acc[1][3] = MFMA16(af1.v, b3, acc[1][3]);
        acc[0][4] = MFMA16(af0.v, b4, acc[0][4]); acc[1][4] = MFMA16(af1.v, b4, acc[1][4]);
        acc[0][5] = MFMA16(af0.v, b5, acc[0][5]); acc[1][5] = MFMA16(af1.v, b5, acc[1][5]);
        acc[0][6] = MFMA16(af0.v, b6, acc[0][6]); acc[1][6] = MFMA16(af1.v, b6, acc[1][6]);
        fb2 += 7;
      } else if (kt < 49) {
        h8 b0 = BRD(0), b1 = BRD(1), b2 = BRD(2);
        acc[0][7] = MFMA16(af0.v, b0, acc[0][7]); acc[1][7] = MFMA16(af1.v, b0, acc[1][7]);
        acc[0][8] = MFMA16(af0.v, b1, acc[0][8]); acc[1][8] = MFMA16(af1.v, b1, acc[1][8]);
        acc[0][9] = MFMA16(af0.v, b2, acc[0][9]); acc[1][9] = MFMA16(af1.v, b2, acc[1][9]);
        fb2 += 3;
      } else {
        h8 b0 = BRD(0);
        acc[0][10] = MFMA16(af0.v, b0, acc[0][10]); acc[1][10] = MFMA16(af1.v, b0, acc[1][10]);
        fb2 += 1;
      }
    }
  };

  // ---- pipelined main loop: 6 chunks of 4 tiles + 1 tail tile; 1 barrier/chunk ----
  issue(T0, 4);
  __syncthreads();           // xT/rtab visible
  wr(bs[0]);
  __syncthreads();
#pragma unroll 1
  for (int ck = 0; ck < 7; ++ck) {
    const int cs = T0 + ck * 4;
    const int ntl = (ck < 6) ? 4 : 1;
    if (ck < 6) issue(cs + 4, (ck < 5) ? 4 : 1);
    consume(cs, ntl, bs[ck & 1]);
    if (ck < 6) {
      wr(bs[(ck & 1) ^ 1]);   // that buffer was consumed a chunk ago, barrier-separated
      __syncthreads();
    }
  }
  __syncthreads();   // all B reads done; safe to alias bs as Ef

  // ---- species fold -> Ef (fp16, K-expanded (ir,cc)), zero-padded ----
  _Float16* Ef = (_Float16*)&bs[0][0];   // [p][ks(16)][lg(4)][o(16)][i(8)] = 32 KB
  {
    float4 z4 = {0.f, 0.f, 0.f, 0.f};
    float4* zp = (float4*)&bs[0][0];
    zp[t] = z4; zp[t + 512] = z4; zp[t + 1024] = z4; zp[t + 1536] = z4;
  }
  __syncthreads();
  {
    const int o = l & 15;
    int ir, ii; o_to_iri(o, ir, ii); (void)ii;
    const int cb = w * 16 + g * 4;
#pragma unroll
    for (int p = 0; p < 2; ++p) {
      const int sp = p ? s1 : s0;
      float tot[4] = {0.f, 0.f, 0.f, 0.f};
#pragma unroll
      for (int k = 0; k < 7; ++k) {
        const float4 wv = *(const float4*)(w3 + ((size_t)(ir * S_SPEC + sp) * 7 + k) * C_CH + cb);
        tot[0] = fmaf(wv.x, acc[p][k][0], tot[0]);
        tot[1] = fmaf(wv.y, acc[p][k][1], tot[1]);
        tot[2] = fmaf(wv.z, acc[p][k][2], tot[2]);
        tot[3] = fmaf(wv.w, acc[p][k][3], tot[3]);
      }
#pragma unroll
      for (int k = 0; k < 3; ++k) {
        const float4 wv = *(const float4*)(w2 + ((size_t)(ir * S_SPEC + sp) * 3 + k) * C_CH + cb);
        tot[0] = fmaf(wv.x, acc[p][7 + k][0], tot[0]);
        tot[1] = fmaf(wv.y, acc[p][7 + k][1], tot[1]);
        tot[2] = fmaf(wv.z, acc[p][7 + k][2], tot[2]);
        tot[3] = fmaf(wv.w, acc[p][7 + k][3], tot[3]);
      }
      {
        const float4 wv = *(const float4*)(w1 + (size_t)(ir * S_SPEC + sp) * C_CH + cb);
        tot[0] = fmaf(wv.x, acc[p][10][0], tot[0]);
        tot[1] = fmaf(wv.y, acc[p][10][1], tot[1]);
        tot[2] = fmaf(wv.z, acc[p][10][2], tot[2]);
        tot[3] = fmaf(wv.w, acc[p][10][3], tot[3]);
      }
#pragma unroll
      for (int r = 0; r < 4; ++r) {
        const int k = ir * 128 + cb + r;   // expanded K index
        Ef[((((size_t)p * 16 + (k >> 5)) * 4 + ((k >> 3) & 3)) * 16 + o) * 8 + (k & 7)] =
            (_Float16)tot[r];
      }
    }
  }
  __syncthreads();

  // ---- wlin channel mix via MFMA; merge K-halves with atomicAdd ----
  {
    f32x4 D0 = {0.f, 0.f, 0.f, 0.f}, D1 = {0.f, 0.f, 0.f, 0.f};
#pragma unroll
    for (int ks = 0; ks < 16; ++ks) {
      const h8 aw = g_Wf[(w * 16 + ks) * 64 + l];
      const h8 b0 = *(const h8*)&Ef[(((size_t)0 * 16 + ks) * 4 + (l >> 4)) * 128 + (size_t)(l & 15) * 8];
      const h8 b1 = *(const h8*)&Ef[(((size_t)1 * 16 + ks) * 4 + (l >> 4)) * 128 + (size_t)(l & 15) * 8];
      D0 = MFMA16(aw, b0, D0);
      D1 = MFMA16(aw, b1, D1);
    }
    const int o = l & 15;
    int ir, ii; o_to_iri(o, ir, ii);
    const int dis[4]  = {1, 3, 5, 7};
    const int ooff[4] = {0, 128, 512, 1152};
#pragma unroll
    for (int p = 0; p < 2; ++p) {
      const f32x4 D = p ? D1 : D0;
      const size_t base = (size_t)(n0 + p) * 2048 + ooff[ir] + ii;
#pragma unroll
      for (int r = 0; r < 4; ++r) {
        const int f = w * 16 + (l >> 4) * 4 + r;
        atomicAdd(&out[base + (size_t)f * dis[ir]], D[r]);
      }
    }
  }
}

// ---------------- launch ----------------

extern "C" void kernel_launch(void* const* d_in, const int* in_sizes, int n_in,
                              void* d_out, int out_size, void* d_ws, size_t ws_size,
                              hipStream_t stream) {
  const float* x      = (const float*)d_in[0];
  const int*   specie = (const int*)d_in[1];

  const float *u1s[4], *u2s[4], *u3s[4];
  if (in_sizes[3] == 768) {  // interleaved dict order: u1_0,u2_0,u3_0,u1_1,...
    for (int i = 0; i < 4; ++i) {
      u1s[i] = (const float*)d_in[2 + 3 * i];
      u2s[i] = (const float*)d_in[3 + 3 * i];
      u3s[i] = (const float*)d_in[4 + 3 * i];
    }
  } else {                   // grouped order: u1_0..u1_3,u2_0..u2_3,u3_0..u3_3
    for (int i = 0; i < 4; ++i) {
      u1s[i] = (const float*)d_in[2 + i];
      u2s[i] = (const float*)d_in[6 + i];
      u3s[i] = (const float*)d_in[10 + i];
    }
  }
  const float* w1   = (const float*)d_in[14];
  const float* w2   = (const float*)d_in[15];
  const float* w3   = (const float*)d_in[16];
  const float* wlin = (const float*)d_in[17];
  float* out = (float*)d_out;
  (void)d_ws; (void)ws_size; (void)n_in;

  hipMemsetAsync(out, 0, (size_t)out_size * sizeof(float), stream);
  build_all<<<448, 64, 0, stream>>>(
      u1s[0], u1s[1], u1s[2], u1s[3],
      u2s[0], u2s[1], u2s[2], u2s[3],
      u3s[0], u3s[1], u3s[2], u3s[3], wlin);
  eqp_mm<<<dim3(N_NODES / 2, 2), 512, 0, stream>>>(x, specie, w1, w2, w3, out);
}

// Round 11
// 62.547 us; speedup vs baseline: 5.2684x; 1.8322x over previous
//
#include <hip/hip_runtime.h>

#define N_NODES 512
#define C_CH    128
#define S_SPEC  10
#define KT      50
#define NT      11

typedef _Float16 h8 __attribute__((ext_vector_type(8)));
typedef float f32x4 __attribute__((ext_vector_type(4)));

// K layout: 50 tiles x 32 slots; tile = 4 octets (one per lane-group g).
// Octet = (offA, offB, j0): slot i computes x[offA]*x[offB]*x[j0+i], j0 in {0,8}.
// N cols (o-major): nt 0..6 = k3, 7..9 = k2, 10 = k1; col = o (0..15).
// Fragment linearization (build & consume order): fi = kt*7+nt (kt<43);
// 301 + (kt-43)*3 + (nt-7) (43<=kt<49); 319 (kt=49).  Total 320 frags.
__device__ h8 g_Bf[KT * NT * 64];   // B pre-swizzled to MFMA B-frag order [kt][nt][lane]
__device__ h8 g_Wf[128 * 64];       // wlin as A-frags: [mt*16+ks][lane], K-expanded (ir,cc)

__device__ __forceinline__ void o_to_iri(int o, int& ir, int& i) {
  if (o >= 9)      { ir = 3; i = o - 9; }
  else if (o >= 4) { ir = 2; i = o - 4; }
  else if (o >= 1) { ir = 1; i = o - 1; }
  else             { ir = 0; i = 0; }
}

__device__ int octet_desc(int Q) {
  if (Q < 172) {                     // order-3
    int q = Q;
    for (int a = 0; a < 16; ++a)
      for (int b = a; b < 16; ++b) {
        int no = (b < 8) ? 2 : 1;
        if (q < no) {
          int jb = (no == 1) ? 1 : q;          // b<8: q0->j0=0,q1->j0=8; b>=8: j0=8
          return a | (b << 5) | (jb << 10);
        }
        q -= no;
      }
  } else if (Q < 196) {              // order-2
    int q = Q - 172;
    for (int a = 0; a < 16; ++a) {
      int no = (a < 8) ? 2 : 1;
      if (q < no) {
        int jb = (no == 1) ? 1 : q;
        return a | (16 << 5) | (jb << 10);
      }
      q -= no;
    }
  } else if (Q < 198) {              // order-1
    return 16 | (16 << 5) | ((Q - 196) << 10);
  }
  return 17 | (17 << 5);             // pad (zero column)
}

// ---- merged build: blocks 0..319 build B fragments, 320..447 build W fragments ----
__global__ void build_all(const float* __restrict__ u1_0, const float* __restrict__ u1_1,
                          const float* __restrict__ u1_2, const float* __restrict__ u1_3,
                          const float* __restrict__ u2_0, const float* __restrict__ u2_1,
                          const float* __restrict__ u2_2, const float* __restrict__ u2_3,
                          const float* __restrict__ u3_0, const float* __restrict__ u3_1,
                          const float* __restrict__ u3_2, const float* __restrict__ u3_3,
                          const float* __restrict__ wlin) {
  const int bid = blockIdx.x;
  const int dis[4] = {1, 3, 5, 7};
  if (bid < 320) {
    int kt, nt;
    if (bid < 301)      { kt = bid / 7; nt = bid % 7; }
    else if (bid < 319) { int e = bid - 301; kt = 43 + e / 3; nt = 7 + e % 3; }
    else                { kt = 49; nt = 10; }

    const int l = threadIdx.x;
    const int o = l & 15;
    int ir, ii; o_to_iri(o, ir, ii);
    const int di = dis[ir];
    const float* u1s[4] = {u1_0, u1_1, u1_2, u1_3};
    const float* u2s[4] = {u2_0, u2_1, u2_2, u2_3};
    const float* u3s[4] = {u3_0, u3_1, u3_2, u3_3};

    const int rt = octet_desc(kt * 4 + (l >> 4));
    const int oA = rt & 31, oB = (rt >> 5) & 31, j0 = ((rt >> 10) & 1) * 8;

    h8 v;
#pragma unroll
    for (int i = 0; i < 8; ++i) {
      const int j = j0 + i;
      float val = 0.f;
      if (oA < 16 && oB < 16) {              // order-3, canonical a<=b<=j
        if (j >= oB) {
          const float* u = u3s[ir];
          int a = oA, b = oB;
          int P[6][3] = {{a,b,j},{a,j,b},{b,a,j},{b,j,a},{j,a,b},{j,b,a}};
          for (int p = 0; p < 6; ++p) {
            bool dup = false;
            for (int r = 0; r < p; ++r)
              if (P[r][0] == P[p][0] && P[r][1] == P[p][1] && P[r][2] == P[p][2]) { dup = true; break; }
            if (!dup)
              val += u[(((P[p][0] * 16 + P[p][1]) * 16 + P[p][2]) * 7 + nt) * di + ii];
          }
        }
      } else if (oA < 16 && oB == 16) {      // order-2 (oA <= j)
        if (j >= oA) {
          const int k2 = nt - 7;
          const float* u = u2s[ir];
          val = u[((oA * 16 + j) * 3 + k2) * di + ii];
          if (j != oA) val += u[((j * 16 + oA) * 3 + k2) * di + ii];
        }
      } else if (oA == 16) {                 // order-1
        val = u1s[ir][j * di + ii];
      }
      v[i] = (_Float16)val;
    }
    g_Bf[((size_t)kt * NT + nt) * 64 + l] = v;
  } else {
    // wlin -> fp16 A-frags over expanded K = (ir*128+cc), scaled by 1/sqrt(128)
    const int id = (bid - 320) * 64 + threadIdx.x;   // 8192 total
    const int l = id & 63, ks = (id >> 6) & 15, mt = id >> 10;
    const int f = mt * 16 + (l & 15);
    const float inv = 0.08838834764831845f;
    h8 v;
#pragma unroll
    for (int i = 0; i < 8; ++i) {
      const int k = ks * 32 + (l >> 4) * 8 + i;
      const int ir = k >> 7, cc = k & 127;
      v[i] = (_Float16)(wlin[((size_t)ir * C_CH + cc) * C_CH + f] * inv);
    }
    g_Wf[(mt * 16 + ks) * 64 + l] = v;
  }
}

// ---------------- fused main kernel: 2 nodes/block, 10-tile chunks, pk-mul production ----
// NOTE: no min-waves in __launch_bounds__ (R1/R4/R8 spilled when capped). 1 block/CU by LDS.

#define MFMA16(A, B, C) __builtin_amdgcn_mfma_f32_16x16x32_f16(A, B, C, 0, 0, 0)

__global__ __launch_bounds__(512, 1) void eqp_mm(
    const float* __restrict__ x, const int* __restrict__ specie,
    const float* __restrict__ w1, const float* __restrict__ w2,
    const float* __restrict__ w3, float* __restrict__ out) {
  __shared__ __align__(16) char bs[2][70 * 1024];   // B chunk double buffer (Ef aliases later)
  __shared__ float xT[2][128][18];                  // cols 0..15 x, 16 = 1, 17 = 0
  __shared__ int rtab[KT * 4];

  const int t = threadIdx.x;
  const int l = t & 63;
  const int w = t >> 6;
  const int g = l >> 4;
  const int n0 = blockIdx.x * 2;

  {  // stage xT + rtab
    const int p = t >> 8, c = (t >> 1) & 127, half = t & 1;
    const float* xp = x + ((size_t)(n0 + p) * C_CH + c) * 16 + half * 8;
    const float4 v0 = *(const float4*)xp, v1 = *(const float4*)(xp + 4);
    float* row = &xT[p][c][half * 8];
    row[0] = v0.x; row[1] = v0.y; row[2] = v0.z; row[3] = v0.w;
    row[4] = v1.x; row[5] = v1.y; row[6] = v1.z; row[7] = v1.w;
    if (half == 1) { xT[p][c][16] = 1.f; xT[p][c][17] = 0.f; }
    if (t < KT * 4) rtab[t] = octet_desc(t);
  }

  const int ch = w * 16 + (l & 15);
  const int s0 = specie[n0], s1 = specie[n0 + 1];

  // pre-convert this lane's channel rows to packed fp16 (RTE) for pk-mul production
  auto packh = [](float4 u, float4 v) {
    h8 r;
    r[0] = (_Float16)u.x; r[1] = (_Float16)u.y; r[2] = (_Float16)u.z; r[3] = (_Float16)u.w;
    r[4] = (_Float16)v.x; r[5] = (_Float16)v.y; r[6] = (_Float16)v.z; r[7] = (_Float16)v.w;
    return r;
  };
  h8 xh0l, xh0h, xh1l, xh1h;
  {
    const float4* p0 = (const float4*)(x + ((size_t)n0 * C_CH + ch) * 16);
    xh0l = packh(p0[0], p0[1]); xh0h = packh(p0[2], p0[3]);
    const float4* p1 = (const float4*)(x + ((size_t)(n0 + 1) * C_CH + ch) * 16);
    xh1l = packh(p1[0], p1[1]); xh1h = packh(p1[2], p1[3]);
  }

  f32x4 acc[2][NT];
#pragma unroll
  for (int p = 0; p < 2; ++p)
#pragma unroll
    for (int i = 0; i < NT; ++i) acc[p][i] = (f32x4){0.f, 0.f, 0.f, 0.f};

  h8 tv[9]; int dst[9];

  auto issue = [&](int ck) {
    const int f0 = ck * 70;
    const int nf = (ck < 4) ? 70 : 40;
#pragma unroll
    for (int slot = 0; slot < 9; ++slot) {
      const int r = slot * 8 + w;
      const bool ok = r < nf;
      const int fi = f0 + r;
      int kt, nt;
      if (fi < 301)      { kt = fi / 7;  nt = fi % 7; }
      else if (fi < 319) { kt = 43 + (fi - 301) / 3; nt = 7 + (fi - 301) % 3; }
      else               { kt = 49; nt = 10; }
      dst[slot] = ok ? r : -1;
      if (ok) tv[slot] = g_Bf[((size_t)kt * NT + nt) * 64 + l];
    }
  };
  auto wr = [&](char* buf) {
#pragma unroll
    for (int slot = 0; slot < 9; ++slot)
      if (dst[slot] >= 0) *(h8*)&buf[(size_t)dst[slot] * 1024 + (size_t)l * 16] = tv[slot];
  };

#define BRD(i) (*(const h8*)&buf[(size_t)(fb2 + (i)) * 1024 + (size_t)l * 16])

  auto consume = [&](int ck, const char* buf) {
    const int cs = ck * 10;
    int fb2 = 0;
#pragma unroll
    for (int tt = 0; tt < 10; ++tt) {
      const int kt = cs + tt;
      const int rt_ = rtab[kt * 4 + g];
      const int oA_ = rt_ & 31, oB_ = (rt_ >> 5) & 31, jb_ = (rt_ >> 10) & 1;
      const float xab0 = xT[0][ch][oA_] * xT[0][ch][oB_];
      const float xab1 = xT[1][ch][oA_] * xT[1][ch][oB_];
      const _Float16 hm0 = (_Float16)xab0, hm1 = (_Float16)xab1;   // RTE
      const h8 m0 = {hm0, hm0, hm0, hm0, hm0, hm0, hm0, hm0};
      const h8 m1 = {hm1, hm1, hm1, hm1, hm1, hm1, hm1, hm1};
      const h8 af0 = m0 * (jb_ ? xh0h : xh0l);   // 4x v_pk_mul_f16
      const h8 af1 = m1 * (jb_ ? xh1h : xh1l);
      if (kt < 43) {
        h8 b0 = BRD(0), b1 = BRD(1), b2 = BRD(2), b3 = BRD(3), b4 = BRD(4), b5 = BRD(5), b6 = BRD(6);
        acc[0][0] = MFMA16(af0, b0, acc[0][0]); acc[1][0] = MFMA16(af1, b0, acc[1][0]);
        acc[0][1] = MFMA16(af0, b1, acc[0][1]); acc[1][1] = MFMA16(af1, b1, acc[1][1]);
        acc[0][2] = MFMA16(af0, b2, acc[0][2]); acc[1][2] = MFMA16(af1, b2, acc[1][2]);
        acc[0][3] = MFMA16(af0, b3, acc[0][3]); acc[1][3] = MFMA16(af1, b3, acc[1][3]);
        acc[0][4] = MFMA16(af0, b4, acc[0][4]); acc[1][4] = MFMA16(af1, b4, acc[1][4]);
        acc[0][5] = MFMA16(af0, b5, acc[0][5]); acc[1][5] = MFMA16(af1, b5, acc[1][5]);
        acc[0][6] = MFMA16(af0, b6, acc[0][6]); acc[1][6] = MFMA16(af1, b6, acc[1][6]);
        fb2 += 7;
      } else if (kt < 49) {
        h8 b0 = BRD(0), b1 = BRD(1), b2 = BRD(2);
        acc[0][7] = MFMA16(af0, b0, acc[0][7]); acc[1][7] = MFMA16(af1, b0, acc[1][7]);
        acc[0][8] = MFMA16(af0, b1, acc[0][8]); acc[1][8] = MFMA16(af1, b1, acc[1][8]);
        acc[0][9] = MFMA16(af0, b2, acc[0][9]); acc[1][9] = MFMA16(af1, b2, acc[1][9]);
        fb2 += 3;
      } else {
        h8 b0 = BRD(0);
        acc[0][10] = MFMA16(af0, b0, acc[0][10]); acc[1][10] = MFMA16(af1, b0, acc[1][10]);
        fb2 += 1;
      }
    }
  };

  // ---- pipelined main loop: 5 chunks of 10 tiles; 1 barrier/chunk ----
  issue(0);
  __syncthreads();           // xT/rtab visible
  wr(bs[0]);
  __syncthreads();
#pragma unroll 1
  for (int ck = 0; ck < 5; ++ck) {
    if (ck < 4) issue(ck + 1);
    consume(ck, bs[ck & 1]);
    if (ck < 4) {
      wr(bs[(ck & 1) ^ 1]);   // that buffer was consumed a chunk ago, barrier-separated
      __syncthreads();
    }
  }
  __syncthreads();   // all B reads done; safe to alias bs as Ef

  // ---- species fold -> Ef (fp16, K-expanded (ir,cc)), zero-padded ----
  _Float16* Ef = (_Float16*)&bs[0][0];   // [p][ks(16)][lg(4)][o(16)][i(8)] = 32 KB
  {
    float4 z4 = {0.f, 0.f, 0.f, 0.f};
    float4* zp = (float4*)&bs[0][0];
    zp[t] = z4; zp[t + 512] = z4; zp[t + 1024] = z4; zp[t + 1536] = z4;
  }
  __syncthreads();
  {
    const int o = l & 15;
    int ir, ii; o_to_iri(o, ir, ii); (void)ii;
    const int cb = w * 16 + g * 4;
#pragma unroll
    for (int p = 0; p < 2; ++p) {
      const int sp = p ? s1 : s0;
      float tot[4] = {0.f, 0.f, 0.f, 0.f};
#pragma unroll
      for (int k = 0; k < 7; ++k) {
        const float4 wv = *(const float4*)(w3 + ((size_t)(ir * S_SPEC + sp) * 7 + k) * C_CH + cb);
        tot[0] = fmaf(wv.x, acc[p][k][0], tot[0]);
        tot[1] = fmaf(wv.y, acc[p][k][1], tot[1]);
        tot[2] = fmaf(wv.z, acc[p][k][2], tot[2]);
        tot[3] = fmaf(wv.w, acc[p][k][3], tot[3]);
      }
#pragma unroll
      for (int k = 0; k < 3; ++k) {
        const float4 wv = *(const float4*)(w2 + ((size_t)(ir * S_SPEC + sp) * 3 + k) * C_CH + cb);
        tot[0] = fmaf(wv.x, acc[p][7 + k][0], tot[0]);
        tot[1] = fmaf(wv.y, acc[p][7 + k][1], tot[1]);
        tot[2] = fmaf(wv.z, acc[p][7 + k][2], tot[2]);
        tot[3] = fmaf(wv.w, acc[p][7 + k][3], tot[3]);
      }
      {
        const float4 wv = *(const float4*)(w1 + (size_t)(ir * S_SPEC + sp) * C_CH + cb);
        tot[0] = fmaf(wv.x, acc[p][10][0], tot[0]);
        tot[1] = fmaf(wv.y, acc[p][10][1], tot[1]);
        tot[2] = fmaf(wv.z, acc[p][10][2], tot[2]);
        tot[3] = fmaf(wv.w, acc[p][10][3], tot[3]);
      }
#pragma unroll
      for (int r = 0; r < 4; ++r) {
        const int k = ir * 128 + cb + r;   // expanded K index
        Ef[((((size_t)p * 16 + (k >> 5)) * 4 + ((k >> 3) & 3)) * 16 + o) * 8 + (k & 7)] =
            (_Float16)tot[r];
      }
    }
  }
  __syncthreads();

  // ---- wlin channel mix via MFMA: D[f][o] = sum_k Wall[f][k] * Ef[k][o] ----
  {
    f32x4 D0 = {0.f, 0.f, 0.f, 0.f}, D1 = {0.f, 0.f, 0.f, 0.f};
#pragma unroll
    for (int ks = 0; ks < 16; ++ks) {
      const h8 aw = g_Wf[(w * 16 + ks) * 64 + l];
      const h8 b0 = *(const h8*)&Ef[(((size_t)0 * 16 + ks) * 4 + (l >> 4)) * 128 + (size_t)(l & 15) * 8];
      const h8 b1 = *(const h8*)&Ef[(((size_t)1 * 16 + ks) * 4 + (l >> 4)) * 128 + (size_t)(l & 15) * 8];
      D0 = MFMA16(aw, b0, D0);
      D1 = MFMA16(aw, b1, D1);
    }
    const int o = l & 15;
    int ir, ii; o_to_iri(o, ir, ii);
    const int dis[4]  = {1, 3, 5, 7};
    const int ooff[4] = {0, 128, 512, 1152};
#pragma unroll
    for (int p = 0; p < 2; ++p) {
      const f32x4 D = p ? D1 : D0;
      const size_t base = (size_t)(n0 + p) * 2048 + ooff[ir] + ii;
#pragma unroll
      for (int r = 0; r < 4; ++r) {
        const int f = w * 16 + (l >> 4) * 4 + r;
        out[base + (size_t)f * dis[ir]] = D[r];
      }
    }
  }
}

// ---------------- launch ----------------

extern "C" void kernel_launch(void* const* d_in, const int* in_sizes, int n_in,
                              void* d_out, int out_size, void* d_ws, size_t ws_size,
                              hipStream_t stream) {
  const float* x      = (const float*)d_in[0];
  const int*   specie = (const int*)d_in[1];

  const float *u1s[4], *u2s[4], *u3s[4];
  if (in_sizes[3] == 768) {  // interleaved dict order: u1_0,u2_0,u3_0,u1_1,...
    for (int i = 0; i < 4; ++i) {
      u1s[i] = (const float*)d_in[2 + 3 * i];
      u2s[i] = (const float*)d_in[3 + 3 * i];
      u3s[i] = (const float*)d_in[4 + 3 * i];
    }
  } else {                   // grouped order: u1_0..u1_3,u2_0..u2_3,u3_0..u3_3
    for (int i = 0; i < 4; ++i) {
      u1s[i] = (const float*)d_in[2 + i];
      u2s[i] = (const float*)d_in[6 + i];
      u3s[i] = (const float*)d_in[10 + i];
    }
  }
  const float* w1   = (const float*)d_in[14];
  const float* w2   = (const float*)d_in[15];
  const float* w3   = (const float*)d_in[16];
  const float* wlin = (const float*)d_in[17];
  float* out = (float*)d_out;
  (void)d_ws; (void)ws_size; (void)out_size; (void)n_in;

  build_all<<<448, 64, 0, stream>>>(
      u1s[0], u1s[1], u1s[2], u1s[3],
      u2s[0], u2s[1], u2s[2], u2s[3],
      u3s[0], u3s[1], u3s[2], u3s[3], wlin);
  eqp_mm<<<N_NODES / 2, 512, 0, stream>>>(x, specie, w1, w2, w3, out);
}